// Round 5
// baseline (257.305 us; speedup 1.0000x reference)
//
#include <hip/hip_runtime.h>
#include <cstdint>

#define BDIM 8192
#define DDIM 128
#define JS 32                 // j-splits: each wave covers 8192/32 = 256 j

// ws layout (bytes)
#define ZH_OFF 0
#define ZL_OFF (2 * 1024 * 1024)
#define RL_OFF (4 * 1024 * 1024)
#define CNT_OFF (RL_OFF + BDIM * 4)
#define P_OFF (RL_OFF + 65536)                 // float2 P2[BDIM][JS] = 2 MB
#define PART_OFF (P_OFF + BDIM * JS * 8)       // float2 part[32]

typedef __attribute__((ext_vector_type(8))) short bf16x8;   // 8 bf16 = 4 VGPRs
typedef __attribute__((ext_vector_type(4))) float f32x4;

__device__ __forceinline__ short f2bf(float f) {            // RTN-even fp32->bf16
  unsigned u = __float_as_uint(f);
  unsigned r = (u + 0x7fffu + ((u >> 16) & 1u)) >> 16;
  return (short)r;
}
__device__ __forceinline__ float bf2f(short h) {
  return __uint_as_float(((unsigned)(unsigned short)h) << 16);
}

// Fragment-tiled Z layout (shorts): element (row,k) at
//   (row>>4)*2048 + (k>>5)*512 + ((k>>3)&3)*128 + (row&15)*8 + (k&7)
// -> one MFMA fragment (16 rows x 8 k) = ONE contiguous 1 KB wave load.

// Kernel 1: blocks 0..511 L2-normalize + bf16 hi/lo split into tiled layout;
// block 512 compacts censor==1 rows via prefix scan (no atomics anywhere).
__global__ __launch_bounds__(256) void ck_prep(
    const float* __restrict__ emb, const int* __restrict__ censor,
    short* __restrict__ ZhT, short* __restrict__ ZlT,
    int* __restrict__ rowlist, int* __restrict__ cnt)
{
  __shared__ float zl[16][132];
  __shared__ float pr[16][16];
  __shared__ float inv[16];
  __shared__ int wtot[4], woff[4];

  const int t = threadIdx.x;
  if (blockIdx.x == 512) {               // ---- compact branch ----
    const int lane = t & 63, wv = t >> 6;
    const int4* c4 = (const int4*)(censor + t * 32);
    unsigned fm = 0;
#pragma unroll
    for (int q = 0; q < 8; ++q) {
      const int4 v = c4[q];
      fm |= (unsigned)(v.x == 1) << (q * 4 + 0);
      fm |= (unsigned)(v.y == 1) << (q * 4 + 1);
      fm |= (unsigned)(v.z == 1) << (q * 4 + 2);
      fm |= (unsigned)(v.w == 1) << (q * 4 + 3);
    }
    const int loc = __popc(fm);
    int sc = loc;                         // inclusive wave scan
#pragma unroll
    for (int m = 1; m < 64; m <<= 1) {
      const int u = __shfl_up(sc, m, 64);
      if (lane >= m) sc += u;
    }
    if (lane == 63) wtot[wv] = sc;
    __syncthreads();
    if (t == 0) {
      int run = 0;
#pragma unroll
      for (int i = 0; i < 4; ++i) { woff[i] = run; run += wtot[i]; }
    }
    __syncthreads();
    int off = woff[wv] + sc - loc;
    for (int u = 0; u < 32; ++u)
      if ((fm >> u) & 1) rowlist[off++] = t * 32 + u;
    if (t == 255) cnt[0] = off;
    return;
  }

  // ---- normalize branch: one 16-row tile per block ----
  const int R = blockIdx.x;
  const int r16 = t >> 4, seg = t & 15;
  const float4* src = (const float4*)(emb + (size_t)(R * 16 + r16) * DDIM + seg * 8);
  const float4 v0 = src[0], v1 = src[1];
  float* zr = &zl[r16][seg * 8];
  zr[0] = v0.x; zr[1] = v0.y; zr[2] = v0.z; zr[3] = v0.w;
  zr[4] = v1.x; zr[5] = v1.y; zr[6] = v1.z; zr[7] = v1.w;
  pr[r16][seg] = v0.x * v0.x + v0.y * v0.y + v0.z * v0.z + v0.w * v0.w +
                 v1.x * v1.x + v1.y * v1.y + v1.z * v1.z + v1.w * v1.w;
  __syncthreads();
  if (t < 16) {
    float ss = 0.f;
#pragma unroll
    for (int s = 0; s < 16; ++s) ss += pr[t][s];
    inv[t] = 1.0f / fmaxf(sqrtf(ss), 1e-12f);   // F.normalize semantics
  }
  __syncthreads();
  const int kc = t >> 6, half = (t >> 4) & 3, r16w = t & 15;
  const float iv = inv[r16w];
  const float* zs = &zl[r16w][(kc * 4 + half) * 8];
  short hs[8], ls[8];
#pragma unroll
  for (int j = 0; j < 8; ++j) {
    const float z = zs[j] * iv;
    const short h = f2bf(z);
    hs[j] = h;
    ls[j] = f2bf(z - bf2f(h));
  }
  const int dst = R * 2048 + t * 8;
  *(bf16x8*)(ZhT + dst) = *(const bf16x8*)hs;
  *(bf16x8*)(ZlT + dst) = *(const bf16x8*)ls;
}

// Kernel 2: software-pipelined register-streaming MFMA sim + masked exp-sums.
// Wave = 64 compacted i-rows x 256 j (8 st-steps of 32 j, 4 kc each = 32 phases).
// A-hi resident (64 VGPR); B hi/lo + A-lo double-buffered, phase p+1 loads
// issued before phase p's 24 MFMAs. Blocks share js across their 4 waves (and
// with block+256 on the same CU) -> L1 B-broadcast. No LDS/barriers/atomics.
__global__ __launch_bounds__(256, 2) void ck_main(
    const short* __restrict__ ZhT, const short* __restrict__ ZlT,
    const int* __restrict__ rowlist, const int* __restrict__ cntp,
    const int* __restrict__ times, float2* __restrict__ P2)
{
  const int cnt = *cntp;
  const int w = threadIdx.x >> 6;
  const int js = blockIdx.x & 31;                 // shared by all 4 waves
  const int iu = (blockIdx.x >> 5) * 4 + w;       // wave's 64-row i-unit
  if (iu * 64 >= cnt) return;
  const int lane = threadIdx.x & 63;
  const int half = lane >> 4;
  const int ll = lane & 15;

  int rbase[4];
#pragma unroll
  for (int a = 0; a < 4; ++a) {
    int c = iu * 64 + a * 16 + ll;
    if (c >= cnt) c = cnt - 1;                    // duplicate; masked at store
    const int r = rowlist[c];
    rbase[a] = (r >> 4) * 2048 + (r & 15) * 8;
  }

  bf16x8 ah[4][4];                                // A-hi resident
#pragma unroll
  for (int a = 0; a < 4; ++a)
#pragma unroll
    for (int kc = 0; kc < 4; ++kc)
      ah[a][kc] = *(const bf16x8*)(ZhT + rbase[a] + kc * 512 + half * 128);

  // packed per-(a,r) metadata for C/D rows (row = half*4 + r):
  // meta = (ti+364)<<16 | gi ; invalid rows: gi=0xFFFF (never matches j),
  // taP=50000 (range test always false).
  int meta[4][4];
#pragma unroll
  for (int a = 0; a < 4; ++a)
#pragma unroll
    for (int r = 0; r < 4; ++r) {
      const int idx = iu * 64 + a * 16 + half * 4 + r;
      const bool vi = idx < cnt;
      const int gi = rowlist[vi ? idx : 0];
      const int taP = vi ? (times[gi] + 364) : 50000;
      meta[a][r] = (taP << 16) | (vi ? gi : 0xFFFF);
    }

  float sd[4][4] = {{0.f}}, sn[4][4] = {{0.f}};
  f32x4 acc[4][2];
#pragma unroll
  for (int a = 0; a < 4; ++a)
#pragma unroll
    for (int b = 0; b < 2; ++b) acc[a][b] = (f32x4){0.f, 0.f, 0.f, 0.f};

  // pipeline buffers (register double-buffers)
  bf16x8 bh[2][2], bl[2][2], alb[2][4];
  int tJ[2][2];                                   // per-st parity
  const int jsT = js * 16;

  auto LP = [&](int p, int par) {                 // issue loads for phase p
    const int st = p >> 2, kc = p & 3;
    const int o = (jsT + st * 2) * 2048 + kc * 512 + lane * 8;
    bh[par][0] = *(const bf16x8*)(ZhT + o);
    bh[par][1] = *(const bf16x8*)(ZhT + o + 2048);
    bl[par][0] = *(const bf16x8*)(ZlT + o);
    bl[par][1] = *(const bf16x8*)(ZlT + o + 2048);
#pragma unroll
    for (int a = 0; a < 4; ++a)
      alb[par][a] = *(const bf16x8*)(ZlT + rbase[a] + kc * 512 + half * 128);
    if (kc == 0) {                                // times for this st (dbuf by st&1)
      const int jb = js * 256 + st * 32;
      tJ[st & 1][0] = times[jb + ll];
      tJ[st & 1][1] = times[jb + 16 + ll];
    }
  };

  LP(0, 0);
#pragma unroll
  for (int p = 0; p < 32; ++p) {
    const int par = p & 1, st = p >> 2, kc = p & 3;
    if (p + 1 < 32) LP(p + 1, par ^ 1);           // prefetch next phase

#pragma unroll
    for (int a = 0; a < 4; ++a)
#pragma unroll
      for (int b = 0; b < 2; ++b)
        acc[a][b] = __builtin_amdgcn_mfma_f32_16x16x32_bf16(ah[a][kc], bh[par][b], acc[a][b], 0, 0, 0);
#pragma unroll
    for (int a = 0; a < 4; ++a)
#pragma unroll
      for (int b = 0; b < 2; ++b)
        acc[a][b] = __builtin_amdgcn_mfma_f32_16x16x32_bf16(ah[a][kc], bl[par][b], acc[a][b], 0, 0, 0);
#pragma unroll
    for (int a = 0; a < 4; ++a)
#pragma unroll
      for (int b = 0; b < 2; ++b)
        acc[a][b] = __builtin_amdgcn_mfma_f32_16x16x32_bf16(alb[par][a], bh[par][b], acc[a][b], 0, 0, 0);

    if (kc == 3) {                                // epilogue for this st
      const int stp = st & 1;
#pragma unroll
      for (int a = 0; a < 4; ++a)
#pragma unroll
        for (int r = 0; r < 4; ++r) {
          const int m_ = meta[a][r];
          const int gi = m_ & 0xFFFF;
          const unsigned taP = ((unsigned)m_) >> 16;
          float d = 0.f, n = 0.f;
#pragma unroll
          for (int b = 0; b < 2; ++b) {
            const int jgb = js * 256 + st * 32 + b * 16 + ll;
            float pv = __expf(fmaf(acc[a][b][r], 10.f, -10.f));  // exp(s-10)
            pv = (gi == jgb) ? 0.f : pv;          // diagonal mask
            d += pv;
            // |ti-tj|<365  <=>  (u32)(ti+364-tj) <= 728
            n += ((unsigned)(taP - (unsigned)tJ[stp][b]) <= 728u) ? pv : 0.f;
          }
          sd[a][r] += d;
          sn[a][r] += n;
        }
#pragma unroll
      for (int a = 0; a < 4; ++a)
#pragma unroll
        for (int b = 0; b < 2; ++b) acc[a][b] = (f32x4){0.f, 0.f, 0.f, 0.f};
    }
  }

  // reduce over ll (lane bits 0..3); one float2 store per valid row
#pragma unroll
  for (int a = 0; a < 4; ++a)
#pragma unroll
    for (int r = 0; r < 4; ++r) {
      float d = sd[a][r], n = sn[a][r];
#pragma unroll
      for (int m = 1; m <= 8; m <<= 1) {
        d += __shfl_xor(d, m, 64);
        n += __shfl_xor(n, m, 64);
      }
      const int idx = iu * 64 + a * 16 + half * 4 + r;
      if (ll == 0 && idx < cnt) P2[(size_t)idx * JS + js] = make_float2(d, n);
    }
}

// Kernel 3: per-row combine over JS splits + log-ratio; block partials.
__global__ __launch_bounds__(256) void ck_fin_a(
    const float2* __restrict__ P2, const int* __restrict__ cntp,
    float2* __restrict__ part)
{
  const int cnt = *cntp;
  const int t = threadIdx.x;
  const int idx = blockIdx.x * 256 + t;
  float lsum = 0.f, lcnt = 0.f;
  if (idx < cnt) {
    const float4* p = (const float4*)(P2 + (size_t)idx * JS);  // 256 B contiguous
    float d = 0.f, n = 0.f;
#pragma unroll
    for (int u = 0; u < 16; ++u) {
      const float4 v = p[u];
      d += v.x + v.z;
      n += v.y + v.w;
    }
    if (n > 0.f) { lsum = logf(d) - logf(n); lcnt = 1.f; }
  }
  __shared__ float s1[256], s2[256];
  s1[t] = lsum; s2[t] = lcnt;
  __syncthreads();
  for (int s = 128; s > 0; s >>= 1) {
    if (t < s) { s1[t] += s1[t + s]; s2[t] += s2[t + s]; }
    __syncthreads();
  }
  if (t == 0) part[blockIdx.x] = make_float2(s1[0], s2[0]);
}

// Kernel 4: final reduce of 32 partials.
__global__ __launch_bounds__(64) void ck_fin_b(
    const float2* __restrict__ part, float* __restrict__ out)
{
  const int t = threadIdx.x;
  float s = 0.f, c = 0.f;
  if (t < 32) { const float2 v = part[t]; s = v.x; c = v.y; }
#pragma unroll
  for (int m = 1; m < 64; m <<= 1) {
    s += __shfl_xor(s, m, 64);
    c += __shfl_xor(c, m, 64);
  }
  if (t == 0) out[0] = (c > 0.f) ? s / fmaxf(c, 1.f) : 0.f;
}

extern "C" void kernel_launch(void* const* d_in, const int* in_sizes, int n_in,
                              void* d_out, int out_size, void* d_ws, size_t ws_size,
                              hipStream_t stream) {
  const float* emb  = (const float*)d_in[0];
  const int* times  = (const int*)d_in[1];
  const int* censor = (const int*)d_in[2];
  float* out = (float*)d_out;

  char* ws = (char*)d_ws;
  short* ZhT   = (short*)(ws + ZH_OFF);
  short* ZlT   = (short*)(ws + ZL_OFF);
  int* rowlist = (int*)(ws + RL_OFF);
  int* cnt     = (int*)(ws + CNT_OFF);
  float2* P2   = (float2*)(ws + P_OFF);
  float2* part = (float2*)(ws + PART_OFF);

  ck_prep<<<513, 256, 0, stream>>>(emb, censor, ZhT, ZlT, rowlist, cnt);
  ck_main<<<1024, 256, 0, stream>>>(ZhT, ZlT, rowlist, cnt, times, P2);
  ck_fin_a<<<32, 256, 0, stream>>>(P2, cnt, part);
  ck_fin_b<<<1, 64, 0, stream>>>(part, out);
}

// Round 7
// 131.895 us; speedup vs baseline: 1.9508x; 1.9508x over previous
//
#include <hip/hip_runtime.h>
#include <cstdint>

#define BDIM 8192
#define DDIM 128
#define JS 32

// ws layout (bytes)
#define ZH_OFF 0
#define ZL_OFF (2 * 1024 * 1024)
#define RL_OFF (4 * 1024 * 1024)
#define CNT_OFF (RL_OFF + BDIM * 4)          // int cnt
#define FC_OFF (CNT_OFF + 64)                // int fin_counter
#define P_OFF (RL_OFF + 65536)               // float2 P2[BDIM][JS] = 2 MB
#define PART_OFF (P_OFF + BDIM * JS * 8)     // float2 part[32]

typedef __attribute__((ext_vector_type(8))) short bf16x8;   // 8 bf16 = 4 VGPRs
typedef __attribute__((ext_vector_type(4))) float f32x4;

__device__ __forceinline__ short f2bf(float f) {            // RTN-even fp32->bf16
  unsigned u = __float_as_uint(f);
  unsigned r = (u + 0x7fffu + ((u >> 16) & 1u)) >> 16;
  return (short)r;
}
__device__ __forceinline__ float bf2f(short h) {
  return __uint_as_float(((unsigned)(unsigned short)h) << 16);
}
__device__ __forceinline__ void gload_lds16(const void* g, void* l) {
  __builtin_amdgcn_global_load_lds(
      (const __attribute__((address_space(1))) unsigned int*)g,
      (__attribute__((address_space(3))) unsigned int*)l, 16, 0, 0);
}

// Fragment-tiled Z layout (shorts): element (row,k) at
//   (row>>4)*2048 + (k>>5)*512 + ((k>>3)&3)*128 + (row&15)*8 + (k&7)
// -> one MFMA fragment (16 rows x 8 k) = contiguous 1 KB per wave; a
//    (j16,kc) unit is 1 KB linear in BOTH global and LDS (direct DMA copy).

// Kernel 1: blocks 0..511 normalize + bf16 hi/lo split (tiled layout);
// block 512 compacts censor==1 rows (prefix scan) and zeroes fin_counter.
__global__ __launch_bounds__(256) void ck_prep(
    const float* __restrict__ emb, const int* __restrict__ censor,
    short* __restrict__ ZhT, short* __restrict__ ZlT,
    int* __restrict__ rowlist, int* __restrict__ cnt, int* __restrict__ fc)
{
  __shared__ float zl[16][132];
  __shared__ float pr[16][16];
  __shared__ float inv[16];
  __shared__ int wtot[4], woff[4];

  const int t = threadIdx.x;
  if (blockIdx.x == 512) {               // ---- compact branch ----
    const int lane = t & 63, wv = t >> 6;
    const int4* c4 = (const int4*)(censor + t * 32);
    unsigned fm = 0;
#pragma unroll
    for (int q = 0; q < 8; ++q) {
      const int4 v = c4[q];
      fm |= (unsigned)(v.x == 1) << (q * 4 + 0);
      fm |= (unsigned)(v.y == 1) << (q * 4 + 1);
      fm |= (unsigned)(v.z == 1) << (q * 4 + 2);
      fm |= (unsigned)(v.w == 1) << (q * 4 + 3);
    }
    const int loc = __popc(fm);
    int sc = loc;                         // inclusive wave scan
#pragma unroll
    for (int m = 1; m < 64; m <<= 1) {
      const int u = __shfl_up(sc, m, 64);
      if (lane >= m) sc += u;
    }
    if (lane == 63) wtot[wv] = sc;
    __syncthreads();
    if (t == 0) {
      int run = 0;
#pragma unroll
      for (int i = 0; i < 4; ++i) { woff[i] = run; run += wtot[i]; }
      fc[0] = 0;                          // zero finalize counter (ws poisoned)
    }
    __syncthreads();
    int off = woff[wv] + sc - loc;
    for (int u = 0; u < 32; ++u)
      if ((fm >> u) & 1) rowlist[off++] = t * 32 + u;
    if (t == 255) cnt[0] = off;
    return;
  }

  // ---- normalize branch: one 16-row tile per block ----
  const int R = blockIdx.x;
  const int r16 = t >> 4, seg = t & 15;
  const float4* src = (const float4*)(emb + (size_t)(R * 16 + r16) * DDIM + seg * 8);
  const float4 v0 = src[0], v1 = src[1];
  float* zr = &zl[r16][seg * 8];
  zr[0] = v0.x; zr[1] = v0.y; zr[2] = v0.z; zr[3] = v0.w;
  zr[4] = v1.x; zr[5] = v1.y; zr[6] = v1.z; zr[7] = v1.w;
  pr[r16][seg] = v0.x * v0.x + v0.y * v0.y + v0.z * v0.z + v0.w * v0.w +
                 v1.x * v1.x + v1.y * v1.y + v1.z * v1.z + v1.w * v1.w;
  __syncthreads();
  if (t < 16) {
    float ss = 0.f;
#pragma unroll
    for (int s = 0; s < 16; ++s) ss += pr[t][s];
    inv[t] = 1.0f / fmaxf(sqrtf(ss), 1e-12f);   // F.normalize semantics
  }
  __syncthreads();
  const int kc = t >> 6, hf = (t >> 4) & 3, rw = t & 15;
  const float iv = inv[rw];
  const float* zs = &zl[rw][(kc * 4 + hf) * 8];
  short hs[8], ls[8];
#pragma unroll
  for (int j = 0; j < 8; ++j) {
    const float z = zs[j] * iv;
    const short h = f2bf(z);
    hs[j] = h;
    ls[j] = f2bf(z - bf2f(h));
  }
  const int dst = R * 2048 + t * 8;
  *(bf16x8*)(ZhT + dst) = *(const bf16x8*)hs;
  *(bf16x8*)(ZlT + dst) = *(const bf16x8*)ls;
}

// Kernel 2: MFMA sim + masked exp-sums. Persistent 512 blocks; block = 256 i
// (4 waves x 64) x 256 j (js = b&31, shared by the block's waves). B hi/lo
// staged into a 2x32KB LDS double buffer via global_load_lds (width 16);
// one barrier per 64-j step, next step's loads issued right after it.
// A-hi register-resident; A-lo streamed per-a (keeps regs < 256 -> no spill).
__global__ __launch_bounds__(256, 2) void ck_main(
    const short* __restrict__ ZhT, const short* __restrict__ ZlT,
    const int* __restrict__ rowlist, const int* __restrict__ cntp,
    const int* __restrict__ times, float2* __restrict__ P2)
{
  __shared__ __align__(16) char lds[65536];
  const int cnt = *cntp;
  const int t = threadIdx.x;
  const int b = blockIdx.x;
  const int lane = t & 63;
  const int w = t >> 6;
  const int half = lane >> 4;
  const int ll = lane & 15;
  const int js = b & 31;
  const int jR0 = js * 16;                 // base j16 unit

  for (int g = b >> 5; g * 256 < cnt; g += 16) {
    int rbase[4];
#pragma unroll
    for (int a = 0; a < 4; ++a) {
      int c = g * 256 + w * 64 + a * 16 + ll;
      if (c >= cnt) c = cnt - 1;           // duplicate valid row; masked at store
      const int r = rowlist[c];
      rbase[a] = (r >> 4) * 2048 + (r & 15) * 8;
    }
    bf16x8 ah[4][4];                       // A-hi resident (64 VGPR)
#pragma unroll
    for (int a = 0; a < 4; ++a)
#pragma unroll
      for (int kc = 0; kc < 4; ++kc)
        ah[a][kc] = *(const bf16x8*)(ZhT + rbase[a] + kc * 512 + half * 128);

    // packed per-(a,r) meta for C/D rows (row = half*4 + r):
    // meta = (ti+364)<<16 | gi ; invalid: gi=0xFFFF, taP=50000 (tests false)
    int meta[4][4];
#pragma unroll
    for (int a = 0; a < 4; ++a)
#pragma unroll
      for (int r = 0; r < 4; ++r) {
        const int idx = g * 256 + w * 64 + a * 16 + half * 4 + r;
        const bool vi = idx < cnt;
        const int gi = rowlist[vi ? idx : 0];
        const int taP = vi ? (times[gi] + 364) : 50000;
        meta[a][r] = (taP << 16) | (vi ? gi : 0xFFFF);
      }

    float sd[4][4] = {{0.f}}, sn[4][4] = {{0.f}};

    // prologue: stage st=0 into buffer 0 (wave w copies 1KB chunks w*8..w*8+7)
    {
      const int c0 = w * 8;
#pragma unroll
      for (int u = 0; u < 8; ++u) {
        const int c = c0 + u, cp = c & 15;
        const short* src = (c < 16) ? ZhT : ZlT;
        const short* gp = src + (size_t)(jR0 + (cp >> 2)) * 2048 + (cp & 3) * 512 + lane * 8;
        gload_lds16(gp, lds + ((c < 16) ? 0 : 16384) + cp * 1024);
      }
    }

    for (int st = 0; st < 4; ++st) {
      __syncthreads();                     // buf[st&1] resident (drains vmcnt)
      if (st < 3) {                        // stage st+1 into other buffer;
        const int pB = ((st + 1) & 1) * 32768;   // drained by NEXT barrier
        const int c0 = w * 8;
#pragma unroll
        for (int u = 0; u < 8; ++u) {
          const int c = c0 + u, cp = c & 15;
          const short* src = (c < 16) ? ZhT : ZlT;
          const short* gp = src + (size_t)(jR0 + (st + 1) * 4 + (cp >> 2)) * 2048 + (cp & 3) * 512 + lane * 8;
          gload_lds16(gp, lds + pB + ((c < 16) ? 0 : 16384) + cp * 1024);
        }
      }

      const char* L = lds + (st & 1) * 32768;
      f32x4 acc[4][4];
#pragma unroll
      for (int a = 0; a < 4; ++a)
#pragma unroll
        for (int bb = 0; bb < 4; ++bb) acc[a][bb] = (f32x4){0.f, 0.f, 0.f, 0.f};

#pragma unroll
      for (int kc = 0; kc < 4; ++kc) {
        bf16x8 bh[4], bl[4];
#pragma unroll
        for (int bb = 0; bb < 4; ++bb) {
          bh[bb] = *(const bf16x8*)(L + bb * 4096 + kc * 1024 + lane * 16);
          bl[bb] = *(const bf16x8*)(L + 16384 + bb * 4096 + kc * 1024 + lane * 16);
        }
#pragma unroll
        for (int a = 0; a < 4; ++a)
#pragma unroll
          for (int bb = 0; bb < 4; ++bb)
            acc[a][bb] = __builtin_amdgcn_mfma_f32_16x16x32_bf16(ah[a][kc], bh[bb], acc[a][bb], 0, 0, 0);
#pragma unroll
        for (int a = 0; a < 4; ++a)
#pragma unroll
          for (int bb = 0; bb < 4; ++bb)
            acc[a][bb] = __builtin_amdgcn_mfma_f32_16x16x32_bf16(ah[a][kc], bl[bb], acc[a][bb], 0, 0, 0);
#pragma unroll
        for (int a = 0; a < 4; ++a) {      // A-lo streamed (one live at a time)
          const bf16x8 alv = *(const bf16x8*)(ZlT + rbase[a] + kc * 512 + half * 128);
#pragma unroll
          for (int bb = 0; bb < 4; ++bb)
            acc[a][bb] = __builtin_amdgcn_mfma_f32_16x16x32_bf16(alv, bh[bb], acc[a][bb], 0, 0, 0);
        }
      }

      // epilogue for this 64-j step: fixed-offset exp-sums (exp(s-10))
      const int jb = js * 256 + st * 64;
      int tJ[4];
#pragma unroll
      for (int bb = 0; bb < 4; ++bb) tJ[bb] = times[jb + bb * 16 + ll];
#pragma unroll
      for (int a = 0; a < 4; ++a)
#pragma unroll
        for (int r = 0; r < 4; ++r) {
          const int m_ = meta[a][r];
          const int gi = m_ & 0xFFFF;
          const unsigned taP = ((unsigned)m_) >> 16;
          float d = 0.f, n = 0.f;
#pragma unroll
          for (int bb = 0; bb < 4; ++bb) {
            const int jgb = jb + bb * 16 + ll;
            float pv = __expf(fmaf(acc[a][bb][r], 10.f, -10.f));
            pv = (gi == jgb) ? 0.f : pv;                 // diagonal mask
            d += pv;
            // |ti-tj|<365  <=>  (u32)(ti+364-tj) <= 728
            n += ((unsigned)(taP - (unsigned)tJ[bb]) <= 728u) ? pv : 0.f;
          }
          sd[a][r] += d;
          sn[a][r] += n;
        }
    }

    // reduce over ll (lane bits 0..3); one float2 store per valid row
#pragma unroll
    for (int a = 0; a < 4; ++a)
#pragma unroll
      for (int r = 0; r < 4; ++r) {
        float d = sd[a][r], n = sn[a][r];
#pragma unroll
        for (int m = 1; m <= 8; m <<= 1) {
          d += __shfl_xor(d, m, 64);
          n += __shfl_xor(n, m, 64);
        }
        const int idx = g * 256 + w * 64 + a * 16 + half * 4 + r;
        if (ll == 0 && idx < cnt) P2[(size_t)idx * JS + js] = make_float2(d, n);
      }
    __syncthreads();   // all waves done with LDS before next g restages
  }
}

// Kernel 3: combine 32 splits + log-ratio; last block (threadfence + counter)
// reduces the 32 block partials and writes out. Single dispatch.
__global__ __launch_bounds__(256) void ck_fin(
    const float2* __restrict__ P2, const int* __restrict__ cntp,
    float2* __restrict__ part, int* __restrict__ fc, float* __restrict__ out)
{
  const int cnt = *cntp;
  const int t = threadIdx.x;
  const int idx = blockIdx.x * 256 + t;
  float lsum = 0.f, lcnt = 0.f;
  if (idx < cnt) {
    const float4* p = (const float4*)(P2 + (size_t)idx * JS);  // 256 B
    float d = 0.f, n = 0.f;
#pragma unroll
    for (int u = 0; u < 16; ++u) {
      const float4 v = p[u];
      d += v.x + v.z;
      n += v.y + v.w;
    }
    if (n > 0.f) { lsum = logf(d) - logf(n); lcnt = 1.f; }
  }
  __shared__ float s1[256], s2[256];
  __shared__ int amLast;
  s1[t] = lsum; s2[t] = lcnt;
  __syncthreads();
  for (int s = 128; s > 0; s >>= 1) {
    if (t < s) { s1[t] += s1[t + s]; s2[t] += s2[t + s]; }
    __syncthreads();
  }
  if (t == 0) {
    part[blockIdx.x] = make_float2(s1[0], s2[0]);
    __threadfence();                        // release partial before signaling
    amLast = (atomicAdd(fc, 1) == gridDim.x - 1);
  }
  __syncthreads();
  if (amLast) {
    __threadfence();                        // acquire others' partials
    float s = 0.f, c = 0.f;
    if (t < 32) { const float2 v = part[t]; s = v.x; c = v.y; }
    if (t < 64) {
#pragma unroll
      for (int m = 1; m < 64; m <<= 1) {
        s += __shfl_xor(s, m, 64);
        c += __shfl_xor(c, m, 64);
      }
      if (t == 0) out[0] = (c > 0.f) ? s / fmaxf(c, 1.f) : 0.f;
    }
  }
}

extern "C" void kernel_launch(void* const* d_in, const int* in_sizes, int n_in,
                              void* d_out, int out_size, void* d_ws, size_t ws_size,
                              hipStream_t stream) {
  const float* emb  = (const float*)d_in[0];
  const int* times  = (const int*)d_in[1];
  const int* censor = (const int*)d_in[2];
  float* out = (float*)d_out;

  char* ws = (char*)d_ws;
  short* ZhT    = (short*)(ws + ZH_OFF);
  short* ZlT    = (short*)(ws + ZL_OFF);
  int* rowlist  = (int*)(ws + RL_OFF);
  int* cntp     = (int*)(ws + CNT_OFF);
  int* fc       = (int*)(ws + FC_OFF);
  float2* P2    = (float2*)(ws + P_OFF);
  float2* part  = (float2*)(ws + PART_OFF);

  ck_prep<<<513, 256, 0, stream>>>(emb, censor, ZhT, ZlT, rowlist, cntp, fc);
  ck_main<<<512, 256, 0, stream>>>(ZhT, ZlT, rowlist, cntp, times, P2);
  ck_fin<<<32, 256, 0, stream>>>(P2, cntp, part, fc, out);
}

// Round 8
// 111.032 us; speedup vs baseline: 2.3174x; 1.1879x over previous
//
#include <hip/hip_runtime.h>
#include <cstdint>

#define BDIM 8192
#define DDIM 128
#define JS 32

// ws layout (bytes)
#define ZH_OFF 0
#define ZL_OFF (2 * 1024 * 1024)
#define RL_OFF (4 * 1024 * 1024)
#define CNT_OFF (RL_OFF + BDIM * 4)          // int cnt
#define FC_OFF (CNT_OFF + 64)                // int fin_counter
#define P_OFF (RL_OFF + 65536)               // float2 P2[BDIM][JS] = 2 MB
#define PART_OFF (P_OFF + BDIM * JS * 8)     // float2 part[32]

typedef __attribute__((ext_vector_type(8))) short bf16x8;   // 8 bf16 = 4 VGPRs
typedef __attribute__((ext_vector_type(4))) float f32x4;

__device__ __forceinline__ short f2bf(float f) {            // RTN-even fp32->bf16
  unsigned u = __float_as_uint(f);
  unsigned r = (u + 0x7fffu + ((u >> 16) & 1u)) >> 16;
  return (short)r;
}
__device__ __forceinline__ float bf2f(short h) {
  return __uint_as_float(((unsigned)(unsigned short)h) << 16);
}
__device__ __forceinline__ void gload_lds16(const void* g, void* l) {
  __builtin_amdgcn_global_load_lds(
      (const __attribute__((address_space(1))) unsigned int*)g,
      (__attribute__((address_space(3))) unsigned int*)l, 16, 0, 0);
}

// Fragment-tiled Z layout (shorts): element (row,k) at
//   (row>>4)*2048 + (k>>5)*512 + ((k>>3)&3)*128 + (row&15)*8 + (k&7)
// -> one MFMA fragment (16 rows x 8 k) = contiguous 1 KB per wave; a
//    (j16,kc) unit is 1 KB linear in BOTH global and LDS (direct DMA copy).

// Kernel 1: blocks 0..511 normalize + bf16 hi/lo split (tiled layout);
// block 512 compacts censor==1 rows (prefix scan) and zeroes fin_counter.
__global__ __launch_bounds__(256) void ck_prep(
    const float* __restrict__ emb, const int* __restrict__ censor,
    short* __restrict__ ZhT, short* __restrict__ ZlT,
    int* __restrict__ rowlist, int* __restrict__ cnt, int* __restrict__ fc)
{
  __shared__ float zl[16][132];
  __shared__ float pr[16][16];
  __shared__ float inv[16];
  __shared__ int wtot[4], woff[4];

  const int t = threadIdx.x;
  if (blockIdx.x == 512) {               // ---- compact branch ----
    const int lane = t & 63, wv = t >> 6;
    const int4* c4 = (const int4*)(censor + t * 32);
    unsigned fm = 0;
#pragma unroll
    for (int q = 0; q < 8; ++q) {
      const int4 v = c4[q];
      fm |= (unsigned)(v.x == 1) << (q * 4 + 0);
      fm |= (unsigned)(v.y == 1) << (q * 4 + 1);
      fm |= (unsigned)(v.z == 1) << (q * 4 + 2);
      fm |= (unsigned)(v.w == 1) << (q * 4 + 3);
    }
    const int loc = __popc(fm);
    int sc = loc;                         // inclusive wave scan
#pragma unroll
    for (int m = 1; m < 64; m <<= 1) {
      const int u = __shfl_up(sc, m, 64);
      if (lane >= m) sc += u;
    }
    if (lane == 63) wtot[wv] = sc;
    __syncthreads();
    if (t == 0) {
      int run = 0;
#pragma unroll
      for (int i = 0; i < 4; ++i) { woff[i] = run; run += wtot[i]; }
      fc[0] = 0;                          // zero finalize counter (ws poisoned)
    }
    __syncthreads();
    int off = woff[wv] + sc - loc;
    for (int u = 0; u < 32; ++u)
      if ((fm >> u) & 1) rowlist[off++] = t * 32 + u;
    if (t == 255) cnt[0] = off;
    return;
  }

  // ---- normalize branch: one 16-row tile per block ----
  const int R = blockIdx.x;
  const int r16 = t >> 4, seg = t & 15;
  const float4* src = (const float4*)(emb + (size_t)(R * 16 + r16) * DDIM + seg * 8);
  const float4 v0 = src[0], v1 = src[1];
  float* zr = &zl[r16][seg * 8];
  zr[0] = v0.x; zr[1] = v0.y; zr[2] = v0.z; zr[3] = v0.w;
  zr[4] = v1.x; zr[5] = v1.y; zr[6] = v1.z; zr[7] = v1.w;
  pr[r16][seg] = v0.x * v0.x + v0.y * v0.y + v0.z * v0.z + v0.w * v0.w +
                 v1.x * v1.x + v1.y * v1.y + v1.z * v1.z + v1.w * v1.w;
  __syncthreads();
  if (t < 16) {
    float ss = 0.f;
#pragma unroll
    for (int s = 0; s < 16; ++s) ss += pr[t][s];
    inv[t] = 1.0f / fmaxf(sqrtf(ss), 1e-12f);   // F.normalize semantics
  }
  __syncthreads();
  const int kc = t >> 6, hf = (t >> 4) & 3, rw = t & 15;
  const float iv = inv[rw];
  const float* zs = &zl[rw][(kc * 4 + hf) * 8];
  short hs[8], ls[8];
#pragma unroll
  for (int j = 0; j < 8; ++j) {
    const float z = zs[j] * iv;
    const short h = f2bf(z);
    hs[j] = h;
    ls[j] = f2bf(z - bf2f(h));
  }
  const int dst = R * 2048 + t * 8;
  *(bf16x8*)(ZhT + dst) = *(const bf16x8*)hs;
  *(bf16x8*)(ZlT + dst) = *(const bf16x8*)ls;
}

// Kernel 2: MFMA sim + masked exp-sums. Block = 128 i (4 waves x 32) x 256 j
// (4 st-steps of 64). Wave tile 32i x 64j (a=2) -> persistent regs fit the
// 128-VGPR cap of __launch_bounds__(256,2): ah 32 + sd/sn 16 + meta 8 + acc
// 32 AGPR; inner loop b-major so only one B hi/lo pair (8 VGPR) is live.
// B hi/lo staged to 2x32KB LDS dbuf via global_load_lds; one barrier per
// st-step, next step's loads issued right after it. NO spill (guard: WRITE).
__global__ __launch_bounds__(256, 2) void ck_main(
    const short* __restrict__ ZhT, const short* __restrict__ ZlT,
    const int* __restrict__ rowlist, const int* __restrict__ cntp,
    const int* __restrict__ times, float2* __restrict__ P2)
{
  __shared__ __align__(16) char lds[65536];
  const int cnt = *cntp;
  const int t = threadIdx.x;
  const int b = blockIdx.x;
  const int it = b >> 5;                   // i-tile (128 rows, compacted)
  const int js = b & 31;                   // j-split (256 j)
  if (it * 128 >= cnt) return;
  const int lane = t & 63;
  const int w = t >> 6;
  const int half = lane >> 4;
  const int ll = lane & 15;
  const int jR0 = js * 16;                 // base j16 unit

  // A-frag rows (A rows m = ll), a = 0..1 -> wave covers 32 i-rows
  int rbase[2];
#pragma unroll
  for (int a = 0; a < 2; ++a) {
    int c = it * 128 + w * 32 + a * 16 + ll;
    if (c >= cnt) c = cnt - 1;             // duplicate valid row; masked at store
    const int r = rowlist[c];
    rbase[a] = (r >> 4) * 2048 + (r & 15) * 8;
  }
  bf16x8 ah[2][4];                         // A-hi resident (32 VGPR)
#pragma unroll
  for (int a = 0; a < 2; ++a)
#pragma unroll
    for (int kc = 0; kc < 4; ++kc)
      ah[a][kc] = *(const bf16x8*)(ZhT + rbase[a] + kc * 512 + half * 128);

  // packed per-(a,r) meta for C/D rows (row = half*4 + r):
  // meta = (ti+364)<<16 | gi ; invalid: gi=0xFFFF, taP=50000 (tests false)
  int meta[2][4];
#pragma unroll
  for (int a = 0; a < 2; ++a)
#pragma unroll
    for (int r = 0; r < 4; ++r) {
      const int idx = it * 128 + w * 32 + a * 16 + half * 4 + r;
      const bool vi = idx < cnt;
      const int gi = rowlist[vi ? idx : 0];
      const int taP = vi ? (times[gi] + 364) : 50000;
      meta[a][r] = (taP << 16) | (vi ? gi : 0xFFFF);
    }

  float sd[2][4] = {{0.f}}, sn[2][4] = {{0.f}};

  // prologue: stage st=0 into buffer 0 (wave w copies 1KB chunks w*8..w*8+7)
  {
    const int c0 = w * 8;
#pragma unroll
    for (int u = 0; u < 8; ++u) {
      const int c = c0 + u, cp = c & 15;
      const short* src = (c < 16) ? ZhT : ZlT;
      const short* gp = src + (size_t)(jR0 + (cp >> 2)) * 2048 + (cp & 3) * 512 + lane * 8;
      gload_lds16(gp, lds + ((c < 16) ? 0 : 16384) + cp * 1024);
    }
  }

  for (int st = 0; st < 4; ++st) {
    __syncthreads();                       // buf[st&1] resident (drains vmcnt)
    if (st < 3) {                          // stage st+1 into other buffer;
      const int pB = ((st + 1) & 1) * 32768;   // drained by NEXT barrier
      const int c0 = w * 8;
#pragma unroll
      for (int u = 0; u < 8; ++u) {
        const int c = c0 + u, cp = c & 15;
        const short* src = (c < 16) ? ZhT : ZlT;
        const short* gp = src + (size_t)(jR0 + (st + 1) * 4 + (cp >> 2)) * 2048 + (cp & 3) * 512 + lane * 8;
        gload_lds16(gp, lds + pB + ((c < 16) ? 0 : 16384) + cp * 1024);
      }
    }

    const char* L = lds + (st & 1) * 32768;
    f32x4 acc[2][4];
#pragma unroll
    for (int a = 0; a < 2; ++a)
#pragma unroll
      for (int bb = 0; bb < 4; ++bb) acc[a][bb] = (f32x4){0.f, 0.f, 0.f, 0.f};

#pragma unroll
    for (int kc = 0; kc < 4; ++kc) {
      bf16x8 alv[2];                       // A-lo streamed (L1-hot after st=0)
#pragma unroll
      for (int a = 0; a < 2; ++a)
        alv[a] = *(const bf16x8*)(ZlT + rbase[a] + kc * 512 + half * 128);
#pragma unroll
      for (int bb = 0; bb < 4; ++bb) {     // b-major: one B hi/lo pair live
        const bf16x8 bhv = *(const bf16x8*)(L + bb * 4096 + kc * 1024 + lane * 16);
        const bf16x8 blv = *(const bf16x8*)(L + 16384 + bb * 4096 + kc * 1024 + lane * 16);
        acc[0][bb] = __builtin_amdgcn_mfma_f32_16x16x32_bf16(ah[0][kc], bhv, acc[0][bb], 0, 0, 0);
        acc[1][bb] = __builtin_amdgcn_mfma_f32_16x16x32_bf16(ah[1][kc], bhv, acc[1][bb], 0, 0, 0);
        acc[0][bb] = __builtin_amdgcn_mfma_f32_16x16x32_bf16(ah[0][kc], blv, acc[0][bb], 0, 0, 0);
        acc[1][bb] = __builtin_amdgcn_mfma_f32_16x16x32_bf16(ah[1][kc], blv, acc[1][bb], 0, 0, 0);
        acc[0][bb] = __builtin_amdgcn_mfma_f32_16x16x32_bf16(alv[0], bhv, acc[0][bb], 0, 0, 0);
        acc[1][bb] = __builtin_amdgcn_mfma_f32_16x16x32_bf16(alv[1], bhv, acc[1][bb], 0, 0, 0);
      }
    }

    // epilogue for this 64-j step: fixed-offset exp-sums (exp(s-10))
    const int jb = js * 256 + st * 64;
    int tJ[4];
#pragma unroll
    for (int bb = 0; bb < 4; ++bb) tJ[bb] = times[jb + bb * 16 + ll];
#pragma unroll
    for (int a = 0; a < 2; ++a)
#pragma unroll
      for (int r = 0; r < 4; ++r) {
        const int m_ = meta[a][r];
        const int gi = m_ & 0xFFFF;
        const unsigned taP = ((unsigned)m_) >> 16;
        float d = 0.f, n = 0.f;
#pragma unroll
        for (int bb = 0; bb < 4; ++bb) {
          const int jgb = jb + bb * 16 + ll;
          float pv = __expf(fmaf(acc[a][bb][r], 10.f, -10.f));
          pv = (gi == jgb) ? 0.f : pv;                 // diagonal mask
          d += pv;
          // |ti-tj|<365  <=>  (u32)(ti+364-tj) <= 728
          n += ((unsigned)(taP - (unsigned)tJ[bb]) <= 728u) ? pv : 0.f;
        }
        sd[a][r] += d;
        sn[a][r] += n;
      }
  }

  // reduce over ll (lane bits 0..3); one float2 store per valid row
#pragma unroll
  for (int a = 0; a < 2; ++a)
#pragma unroll
    for (int r = 0; r < 4; ++r) {
      float d = sd[a][r], n = sn[a][r];
#pragma unroll
      for (int m = 1; m <= 8; m <<= 1) {
        d += __shfl_xor(d, m, 64);
        n += __shfl_xor(n, m, 64);
      }
      const int idx = it * 128 + w * 32 + a * 16 + half * 4 + r;
      if (ll == 0 && idx < cnt) P2[(size_t)idx * JS + js] = make_float2(d, n);
    }
}

// Kernel 3: combine 32 splits + log-ratio; last block (threadfence + counter)
// reduces the 32 block partials and writes out. Single dispatch.
__global__ __launch_bounds__(256) void ck_fin(
    const float2* __restrict__ P2, const int* __restrict__ cntp,
    float2* __restrict__ part, int* __restrict__ fc, float* __restrict__ out)
{
  const int cnt = *cntp;
  const int t = threadIdx.x;
  const int idx = blockIdx.x * 256 + t;
  float lsum = 0.f, lcnt = 0.f;
  if (idx < cnt) {
    const float4* p = (const float4*)(P2 + (size_t)idx * JS);  // 256 B
    float d = 0.f, n = 0.f;
#pragma unroll
    for (int u = 0; u < 16; ++u) {
      const float4 v = p[u];
      d += v.x + v.z;
      n += v.y + v.w;
    }
    if (n > 0.f) { lsum = logf(d) - logf(n); lcnt = 1.f; }
  }
  __shared__ float s1[256], s2[256];
  __shared__ int amLast;
  s1[t] = lsum; s2[t] = lcnt;
  __syncthreads();
  for (int s = 128; s > 0; s >>= 1) {
    if (t < s) { s1[t] += s1[t + s]; s2[t] += s2[t + s]; }
    __syncthreads();
  }
  if (t == 0) {
    part[blockIdx.x] = make_float2(s1[0], s2[0]);
    __threadfence();                        // release partial before signaling
    amLast = (atomicAdd(fc, 1) == gridDim.x - 1);
  }
  __syncthreads();
  if (amLast) {
    __threadfence();                        // acquire others' partials
    float s = 0.f, c = 0.f;
    if (t < 32) { const float2 v = part[t]; s = v.x; c = v.y; }
    if (t < 64) {
#pragma unroll
      for (int m = 1; m < 64; m <<= 1) {
        s += __shfl_xor(s, m, 64);
        c += __shfl_xor(c, m, 64);
      }
      if (t == 0) out[0] = (c > 0.f) ? s / fmaxf(c, 1.f) : 0.f;
    }
  }
}

extern "C" void kernel_launch(void* const* d_in, const int* in_sizes, int n_in,
                              void* d_out, int out_size, void* d_ws, size_t ws_size,
                              hipStream_t stream) {
  const float* emb  = (const float*)d_in[0];
  const int* times  = (const int*)d_in[1];
  const int* censor = (const int*)d_in[2];
  float* out = (float*)d_out;

  char* ws = (char*)d_ws;
  short* ZhT    = (short*)(ws + ZH_OFF);
  short* ZlT    = (short*)(ws + ZL_OFF);
  int* rowlist  = (int*)(ws + RL_OFF);
  int* cntp     = (int*)(ws + CNT_OFF);
  int* fc       = (int*)(ws + FC_OFF);
  float2* P2    = (float2*)(ws + P_OFF);
  float2* part  = (float2*)(ws + PART_OFF);

  ck_prep<<<513, 256, 0, stream>>>(emb, censor, ZhT, ZlT, rowlist, cntp, fc);
  ck_main<<<64 * 32, 256, 0, stream>>>(ZhT, ZlT, rowlist, cntp, times, P2);
  ck_fin<<<32, 256, 0, stream>>>(P2, cntp, part, fc, out);
}